// Round 5
// baseline (327.592 us; speedup 1.0000x reference)
//
#include <hip/hip_runtime.h>
#include <math.h>

// ASFF_2: N=8, C1=256, C2=512, H=64, W=64, low-res 32x32.
//  K1 down_gemm: ktT = bf16T(w_down @ input2 + b_down)  [N,34*34,128] padded
//  K2 enc_mfma: kt2 = 9-tap shifted MFMA GEMM           [N,36,1024] fp32
//  K3 softmax -> mask [N,1024,36]
//  K4 CARAFE apply -> hires bf16 [ci][p]                [N,512,4096]
//  K4b transpose -> hiresT bf16 [p][ci]
//  K5 LDS-staged MFMA gemm: u = w_up @ hiresT + b_up    [N,256,4096]  (512 thr)
//  K6 fuse_weights: lw0[n][p] (softmax-over-2 of level attention)
//  K6b transpose_blend: fusedT = bf16(i1*lw0 + u*lw1), padded [66x66][ci]
//  K7 LDS-staged 9-tap MFMA conv + BN + SiLU -> out     (512 thr)

#define EPS 1e-5f
typedef unsigned short u16;
typedef __attribute__((ext_vector_type(8))) __bf16 bf16x8;
typedef __attribute__((ext_vector_type(4))) float f32x4;

__device__ inline u16 f2bf(float x) {
    union { float f; unsigned u; } v; v.f = x;
    unsigned r = v.u + 0x7FFF + ((v.u >> 16) & 1);
    return (u16)(r >> 16);
}

// ---------------- K1: fp32 tiled GEMM, bf16-transposed-padded output ----------------
__global__ __launch_bounds__(256) void down_gemm_kernel(
    const float* __restrict__ A, const float* __restrict__ B,
    const float* __restrict__ bias, u16* __restrict__ ktT)
{
    const int n = blockIdx.z;
    const float* Bn = B + (long)n * 512 * 1024;
    __shared__ __align__(16) float As[16][68];
    __shared__ __align__(16) float Bs[16][64];
    const int tid = threadIdx.x;
    const int tcol = tid & 15;
    const int trow = tid >> 4;
    const int rowBase = blockIdx.y * 64;
    const int colBase = blockIdx.x * 64;
    float acc[4][4] = {};
    for (int k0 = 0; k0 < 512; k0 += 16) {
#pragma unroll
        for (int i = 0; i < 4; ++i) {
            int idx = i * 256 + tid;
            int r = idx >> 4, cc = idx & 15;
            As[cc][r] = A[(long)(rowBase + r) * 512 + k0 + cc];
        }
#pragma unroll
        for (int i = 0; i < 4; ++i) {
            int idx = i * 256 + tid;
            int r = idx >> 6, cc = idx & 63;
            Bs[r][cc] = Bn[(long)(k0 + r) * 1024 + colBase + cc];
        }
        __syncthreads();
#pragma unroll
        for (int kk = 0; kk < 16; ++kk) {
            float4 a4 = *reinterpret_cast<const float4*>(&As[kk][trow * 4]);
            float4 b4 = *reinterpret_cast<const float4*>(&Bs[kk][tcol * 4]);
            float a[4] = {a4.x, a4.y, a4.z, a4.w};
            float b[4] = {b4.x, b4.y, b4.z, b4.w};
#pragma unroll
            for (int i = 0; i < 4; ++i)
#pragma unroll
                for (int j = 0; j < 4; ++j)
                    acc[i][j] += a[i] * b[j];
        }
        __syncthreads();
    }
    u16* Kn = ktT + (long)n * 1156 * 128;
#pragma unroll
    for (int i = 0; i < 4; ++i) {
        int ch = rowBase + trow * 4 + i;
        float bv = bias[ch];
#pragma unroll
        for (int j = 0; j < 4; ++j) {
            int p = colBase + tcol * 4 + j;
            int pr = ((p >> 5) + 1) * 34 + (p & 31) + 1;
            Kn[pr * 128 + ch] = f2bf(acc[i][j] + bv);
        }
    }
}

// ---------------- K2: encoder conv as 9-tap shifted MFMA GEMM ----------------
__global__ __launch_bounds__(64) void enc_mfma_kernel(
    const u16* __restrict__ A, const u16* __restrict__ B,
    const float* __restrict__ bias, float* __restrict__ C)
{
    const int n = blockIdx.y;
    const int lane = threadIdx.x;
    const int lr = lane & 15, lk = lane >> 4;
    const int p = blockIdx.x * 16 + lr;
    const int pr = ((p >> 5) + 1) * 34 + (p & 31) + 1;
    const u16* Bn = B + (long)n * 1156 * 128;
    const int bOff = pr * 128 + lk * 8;
    f32x4 acc[3] = {};
    for (int t = 0; t < 9; ++t) {
        const u16* At = A + t * 8192;
        const int btap = ((t / 3 - 1) * 34 + (t % 3 - 1)) * 128;
#pragma unroll
        for (int k0 = 0; k0 < 128; k0 += 32) {
            bf16x8 bf = *(const bf16x8*)(Bn + bOff + btap + k0);
#pragma unroll
            for (int mf = 0; mf < 3; ++mf) {
                bf16x8 af = *(const bf16x8*)(At + (mf * 16 + lr) * 128 + lk * 8 + k0);
                acc[mf] = __builtin_amdgcn_mfma_f32_16x16x32_bf16(af, bf, acc[mf], 0, 0, 0);
            }
        }
    }
    float* Cn = C + (long)n * 36 * 1024;
#pragma unroll
    for (int mf = 0; mf < 3; ++mf)
#pragma unroll
        for (int reg = 0; reg < 4; ++reg) {
            int co = mf * 16 + lk * 4 + reg;
            if (co < 36)
                Cn[(long)co * 1024 + p] = acc[mf][reg] + bias[co];
        }
}

// ---------------- K3: softmax over k=9 ----------------
__global__ __launch_bounds__(256) void mask_softmax_kernel(
    const float* __restrict__ kt2, float* __restrict__ mask)
{
    int gid = blockIdx.x * 256 + threadIdx.x;   // N*1024*4
    int q = gid & 3;
    int p = (gid >> 2) & 1023;
    int n = gid >> 12;
    float s[9];
    float mx = -1e30f;
#pragma unroll
    for (int k = 0; k < 9; ++k) {
        s[k] = kt2[(long)(n * 36 + k * 4 + q) * 1024 + p];
        mx = fmaxf(mx, s[k]);
    }
    float sum = 0.f;
#pragma unroll
    for (int k = 0; k < 9; ++k) { s[k] = expf(s[k] - mx); sum += s[k]; }
    float inv = 1.f / sum;
    float* mp = mask + (long)(n * 1024 + p) * 36 + q;
#pragma unroll
    for (int k = 0; k < 9; ++k) mp[k * 4] = s[k] * inv;
}

// ---------------- K4: CARAFE apply -> hires bf16 [ci][p] ----------------
__global__ __launch_bounds__(256) void carafe_kernel(
    const float* __restrict__ in2, const float* __restrict__ mask,
    u16* __restrict__ hires)
{
    int bx = blockIdx.x;            // N*32*64 : (n, h, cgroup)
    int cg = bx & 63;
    int h = (bx >> 6) & 31;
    int n = bx >> 11;
    int tid = threadIdx.x;
    int w = tid & 31;
    int cl = tid >> 5;
    int c = cg * 8 + cl;
    __shared__ float mrow[32 * 37];
    const float* mg = mask + (long)(n * 1024 + h * 32) * 36;
    for (int idx = tid; idx < 32 * 36; idx += 256) {
        int pw = idx / 36, j = idx - pw * 36;
        mrow[pw * 37 + j] = mg[idx];
    }
    __syncthreads();
    const float* ip = in2 + (long)(n * 512 + c) * 1024;
    float acc[4] = {0.f, 0.f, 0.f, 0.f};
#pragma unroll
    for (int k = 0; k < 9; ++k) {
        int dh = k / 3 - 1, dw = k % 3 - 1;
        int hh = h + dh, ww = w + dw;
        float val = (hh >= 0 && hh < 32 && ww >= 0 && ww < 32) ? ip[hh * 32 + ww] : 0.f;
#pragma unroll
        for (int q = 0; q < 4; ++q)
            acc[q] += val * mrow[w * 37 + k * 4 + q];
    }
    u16* op = hires + (long)(n * 512 + c) * 4096;
#pragma unroll
    for (int q = 0; q < 4; ++q) {
        int r1 = q >> 1, r2 = q & 1;
        op[(2 * h + r1) * 64 + 2 * w + r2] = f2bf(acc[q]);
    }
}

// ---------------- K4b: transpose hires [512][4096] -> hiresT [p][512] ----------------
__global__ __launch_bounds__(256) void transpose_kernel(
    const u16* __restrict__ src0, u16* __restrict__ dst)
{
    constexpr int C = 512, CP = 514;
    __shared__ u16 lds[32 * CP];
    const int n = blockIdx.y;
    const int p0 = blockIdx.x * 32;
    const int tid = threadIdx.x;
    {
        const int w = tid & 31;
        const int chunk = tid >> 5;
        const u16* src = src0 + (long)n * C * 4096 + p0 + w;
        for (int ci = chunk * 64; ci < chunk * 64 + 64; ++ci)
            lds[w * CP + ci] = src[(long)ci * 4096];
    }
    __syncthreads();
    const int px = tid >> 3;
    const int q = tid & 7;
    u16* drow = dst + (long)n * 4096 * C + (long)(p0 + px) * C;
    const u16* lrow = lds + px * CP;
#pragma unroll
    for (int j = 0; j < C / 16; ++j) {
        int off = j * 16 + q * 2;
        *(unsigned*)(drow + off) = *(const unsigned*)(lrow + off);
    }
}

// ---------------- K6b: fused blend + transpose-cast to padded fusedT ----------------
__global__ __launch_bounds__(256) void transpose_blend_kernel(
    const float* __restrict__ i1g, const float* __restrict__ ug,
    const float* __restrict__ lw0g, u16* __restrict__ dst)
{
    constexpr int C = 256, CP = 258;
    __shared__ u16 lds[32 * CP];
    const int n = blockIdx.y;
    const int p0 = blockIdx.x * 32;
    const int tid = threadIdx.x;
    {
        const int w = tid & 31;
        const int chunk = tid >> 5;
        const int p = p0 + w;
        const float lw = lw0g[n * 4096 + p];
        const float lw1 = 1.f - lw;
        const float* s1 = i1g + (long)n * C * 4096 + p;
        const float* s2 = ug + (long)n * C * 4096 + p;
        for (int ci = chunk * 32; ci < chunk * 32 + 32; ++ci)
            lds[w * CP + ci] = f2bf(s1[(long)ci * 4096] * lw + s2[(long)ci * 4096] * lw1);
    }
    __syncthreads();
    const int px = tid >> 3;
    const int q = tid & 7;
    const int p = p0 + px;
    long prow = (long)((p >> 6) + 1) * 66 + (p & 63) + 1;
    u16* drow = dst + (long)n * 4356 * C + prow * C;
    const u16* lrow = lds + px * CP;
#pragma unroll
    for (int j = 0; j < C / 16; ++j) {
        int off = j * 16 + q * 2;
        *(unsigned*)(drow + off) = *(const unsigned*)(lrow + off);
    }
}

// ---------------- K5/K7: LDS-staged MFMA shifted-GEMM, 8 waves ----------------
// 128x128 tile, waves 2M x 4N (wave tile 64x32). B staged per 32-ci step via
// global_load_lds(16B), double-buffered, region covers all NT taps. XOR swizzle
// applied on pre-swizzled global source; inverse on ds_read.
#define STAGE(bufi, k0s)                                                              \
    for (int i = wid; i < NLOAD; i += 8) {                                            \
        int f = i * 64 + lane;                                                        \
        int r = f >> 2;                                                               \
        int p16 = (f & 3) ^ ((r >> 2) & 3);                                           \
        const u16* gsrc = Bn + (long)(g0 + r) * KC + (k0s) + p16 * 8;                 \
        __builtin_amdgcn_global_load_lds(                                             \
            (const __attribute__((address_space(1))) void*)gsrc,                      \
            (__attribute__((address_space(3))) void*)(lds + (bufi) * BUFU + i * 512), \
            16, 0, 0);                                                                \
    }

template<int KC, int NT, bool PADDED>
__global__ __launch_bounds__(512, 4) void mfma_conv_lds_kernel(
    const u16* __restrict__ A,      // [NT][256][KC] bf16
    const u16* __restrict__ B,      // per image [rows][KC] bf16
    const float* __restrict__ scale, const float* __restrict__ shift,
    float* __restrict__ C, long strideB, long strideC, int silu)
{
    constexpr int RROWS = PADDED ? 272 : 128;   // 264 real + 8 overshoot (never read)
    constexpr int NLOAD = RROWS / 16;           // 17 : 8 loads per buffer
    constexpr int BUFU  = RROWS * 32;           // u16 per buffer
    __shared__ __align__(16) u16 lds[2 * BUFU];
    const int n = blockIdx.z;
    const u16* Bn = B + (long)n * strideB;
    float* Cn = C + (long)n * strideC;
    const int tid = threadIdx.x;
    const int lane = tid & 63;
    const int wid = tid >> 6;                   // 0..7
    const int mw = wid >> 2, nw = wid & 3;      // 2M x 4N
    const int lr = lane & 15, lk = lane >> 4;
    const int rowBase = blockIdx.y * 128;
    const int colBase = blockIdx.x * 128;
    const int g0 = PADDED ? (colBase >> 6) * 66 : colBase;

    long aBase[4];
#pragma unroll
    for (int mf = 0; mf < 4; ++mf)
        aBase[mf] = (long)(rowBase + mw * 64 + mf * 16 + lr) * KC + lk * 8;

    f32x4 acc[4][2] = {};
    bf16x8 af[4], afn[4];
#pragma unroll
    for (int mf = 0; mf < 4; ++mf)
        af[mf] = *(const bf16x8*)(A + aBase[mf]);       // (t=0, k0=0)
    STAGE(0, 0);

    constexpr int NK = KC / 32;
    int cur = 0;
    for (int kx = 0; kx < NK; ++kx) {
        __syncthreads();                                 // drains staging of lds[cur]
        if (kx + 1 < NK) { STAGE(cur ^ 1, (kx + 1) * 32); }
#pragma unroll
        for (int t = 0; t < NT; ++t) {
            // prefetch A for next tap (or next k0's tap 0)
            int tn = (t + 1 == NT) ? 0 : t + 1;
            int kn = (t + 1 == NT) ? ((kx + 1 < NK) ? (kx + 1) * 32 : 0) : kx * 32;
            const u16* An = A + (long)tn * 256 * KC + kn;
#pragma unroll
            for (int mf = 0; mf < 4; ++mf)
                afn[mf] = *(const bf16x8*)(An + aBase[mf]);
            int rb;
            if (PADDED) {
                int dh = t / 3 - 1, dw = t % 3 - 1;
                rb = ((nw >> 1) + dh + 1) * 66 + dw + 1 + (nw & 1) * 32 + lr;
            } else {
                rb = nw * 32 + lr;
            }
            bf16x8 bfr[2];
#pragma unroll
            for (int nf = 0; nf < 2; ++nf) {
                int r = rb + nf * 16;
                bfr[nf] = *(const bf16x8*)(lds + cur * BUFU + r * 32 + (lk ^ ((r >> 2) & 3)) * 8);
            }
#pragma unroll
            for (int mf = 0; mf < 4; ++mf)
#pragma unroll
                for (int nf = 0; nf < 2; ++nf)
                    acc[mf][nf] = __builtin_amdgcn_mfma_f32_16x16x32_bf16(
                        af[mf], bfr[nf], acc[mf][nf], 0, 0, 0);
#pragma unroll
            for (int mf = 0; mf < 4; ++mf) af[mf] = afn[mf];
        }
        cur ^= 1;
    }
#pragma unroll
    for (int mf = 0; mf < 4; ++mf) {
#pragma unroll
        for (int reg = 0; reg < 4; ++reg) {
            int co = rowBase + mw * 64 + mf * 16 + lk * 4 + reg;
            float sc = scale[co], sh = shift[co];
#pragma unroll
            for (int nf = 0; nf < 2; ++nf) {
                int col = colBase + nw * 32 + nf * 16 + lr;
                float y = acc[mf][nf][reg] * sc + sh;
                if (silu) y = y / (1.f + expf(-y));
                Cn[(long)co * 4096 + col] = y;
            }
        }
    }
}

// ---------------- K6: level weights (softmax over 2) -> lw0[n][p] ----------------
__global__ __launch_bounds__(256) void fuse_weights_kernel(
    const float* __restrict__ input1, const float* __restrict__ u,
    const float* __restrict__ w_l1, const float* __restrict__ bn_l1,
    const float* __restrict__ w_l2, const float* __restrict__ bn_l2,
    const float* __restrict__ w_wl, const float* __restrict__ b_wl,
    float* __restrict__ lw0g)
{
    int bx = blockIdx.x;            // 8 * 64
    int n = bx >> 6;
    int p0 = (bx & 63) * 64;
    int tid = threadIdx.x;
    int pos = tid & 63;
    int chunk = tid >> 6;
    int p = p0 + pos;
    const float* i1 = input1 + (long)n * 256 * 4096;
    const float* i2 = u + (long)n * 256 * 4096;
    float s1[8] = {}, s2[8] = {};
    for (int ci = chunk * 64; ci < chunk * 64 + 64; ++ci) {
        float x1 = i1[(long)ci * 4096 + p];
        float x2 = i2[(long)ci * 4096 + p];
#pragma unroll
        for (int j = 0; j < 8; ++j) {
            s1[j] += w_l1[j * 256 + ci] * x1;
            s2[j] += w_l2[j * 256 + ci] * x2;
        }
    }
    __shared__ float red[4][64][16];
#pragma unroll
    for (int j = 0; j < 8; ++j) { red[chunk][pos][j] = s1[j]; red[chunk][pos][8 + j] = s2[j]; }
    __syncthreads();
    if (tid < 64) {
        float v[16];
#pragma unroll
        for (int j = 0; j < 16; ++j)
            v[j] = red[0][tid][j] + red[1][tid][j] + red[2][tid][j] + red[3][tid][j];
        float z0 = b_wl[0], z1 = b_wl[1];
#pragma unroll
        for (int j = 0; j < 8; ++j) {
            float g = bn_l1[j], b = bn_l1[8 + j], m = bn_l1[16 + j], va = bn_l1[24 + j];
            float y = (v[j] - m) * (g * rsqrtf(va + EPS)) + b;
            float sv = y / (1.f + expf(-y));
            z0 += w_wl[j] * sv;
            z1 += w_wl[16 + j] * sv;
            g = bn_l2[j]; b = bn_l2[8 + j]; m = bn_l2[16 + j]; va = bn_l2[24 + j];
            y = (v[8 + j] - m) * (g * rsqrtf(va + EPS)) + b;
            sv = y / (1.f + expf(-y));
            z0 += w_wl[8 + j] * sv;
            z1 += w_wl[24 + j] * sv;
        }
        lw0g[n * 4096 + p0 + tid] = 1.f / (1.f + expf(z1 - z0));
    }
}

// ---------------- prep kernels ----------------
__global__ __launch_bounds__(256) void prep_w_kernel(
    const float* __restrict__ w_conv, const float* __restrict__ w_up,
    const float* __restrict__ w_enc,
    u16* __restrict__ wT, u16* __restrict__ wupT, u16* __restrict__ wencT)
{
    int gid = blockIdx.x * 256 + threadIdx.x;
    if (gid < 589824) {             // wT[t][co][ci] = w_conv[co][ci][t]
        int t = gid >> 16;
        int co = (gid >> 8) & 255;
        int ci = gid & 255;
        wT[gid] = f2bf(w_conv[(co * 256 + ci) * 9 + t]);
    }
    if (gid < 131072) wupT[gid] = f2bf(w_up[gid]);
    if (gid < 73728) {              // wencT[t][co<64][ci] (zeros co>=36)
        int t = gid >> 13;
        int co = (gid >> 7) & 63;
        int ci = gid & 127;
        wencT[gid] = (co < 36) ? f2bf(w_enc[(co * 128 + ci) * 9 + t]) : (u16)0;
    }
}

__global__ void prep_bn_kernel(const float* __restrict__ bn_conv,
                               const float* __restrict__ b_up, float* __restrict__ bnp)
{
    int i = threadIdx.x;            // 256
    float g = bn_conv[i], b = bn_conv[256 + i], m = bn_conv[512 + i], v = bn_conv[768 + i];
    float sc = g * rsqrtf(v + EPS);
    bnp[i] = sc;
    bnp[256 + i] = b - m * sc;
    bnp[512 + i] = 1.f;
    bnp[768 + i] = b_up[i];
}

extern "C" void kernel_launch(void* const* d_in, const int* in_sizes, int n_in,
                              void* d_out, int out_size, void* d_ws, size_t ws_size,
                              hipStream_t stream)
{
    const float* input1 = (const float*)d_in[0];
    const float* input2 = (const float*)d_in[1];
    const float* w_down = (const float*)d_in[2];
    const float* b_down = (const float*)d_in[3];
    const float* w_enc  = (const float*)d_in[4];
    const float* b_enc  = (const float*)d_in[5];
    const float* w_up   = (const float*)d_in[6];
    const float* b_up   = (const float*)d_in[7];
    const float* w_l1   = (const float*)d_in[8];
    const float* bn_l1  = (const float*)d_in[9];
    const float* w_l2   = (const float*)d_in[10];
    const float* bn_l2  = (const float*)d_in[11];
    const float* w_wl   = (const float*)d_in[12];
    const float* b_wl   = (const float*)d_in[13];
    const float* w_conv = (const float*)d_in[14];
    const float* bn_conv= (const float*)d_in[15];
    float* out = (float*)d_out;

    // workspace layout (float units). ~108 MB total.
    float* ws     = (float*)d_ws;
    float* ktTf   = ws;                      //   591,872 f : ktT bf16 [n][1156][128]
    float* wencTf = ktTf + 591872;           //    36,864 f : wencT bf16 [9][64][128]
    float* kt2    = wencTf + 36864;          //   294,912 f
    float* maskb  = kt2 + 294912;            //   294,912 f
    float* u      = maskb + 294912;          // 8,388,608 f
    float* hireb  = u + 8388608;             // 8,388,608 f : hires bf16 [ci][p]
    float* btb    = hireb + 8388608;         // 8,388,608 f : hiresT / fusedT bf16
    float* wTf    = btb + 8388608;           //   294,912 f
    float* wupTf  = wTf + 294912;            //    65,536 f
    float* bnp    = wupTf + 65536;           //     1,024 f
    float* lw0g   = bnp + 1024;              //    32,768 f : lw0 [8][4096]
    u16* ktT      = (u16*)ktTf;
    u16* wencT    = (u16*)wencTf;
    u16* hires_bf = (u16*)hireb;
    u16* bt       = (u16*)btb;
    u16* wT       = (u16*)wTf;
    u16* wupT     = (u16*)wupTf;

    // prep (independent of data pipeline)
    prep_w_kernel<<<dim3(2304), 256, 0, stream>>>(w_conv, w_up, w_enc, wT, wupT, wencT);
    prep_bn_kernel<<<dim3(1), 256, 0, stream>>>(bn_conv, b_up, bnp);

    // K1: ktT = bf16T(w_down @ input2 + b_down), padded 34x34 grid
    hipMemsetAsync(ktT, 0, 8L * 1156 * 128 * 2, stream);
    down_gemm_kernel<<<dim3(16, 2, 8), 256, 0, stream>>>(w_down, input2, b_down, ktT);
    // K2: kt2 = 9-tap shifted MFMA GEMM
    enc_mfma_kernel<<<dim3(64, 8), 64, 0, stream>>>(wencT, ktT, b_enc, kt2);
    // K3
    mask_softmax_kernel<<<dim3(128), 256, 0, stream>>>(kt2, maskb);
    // K4: CARAFE -> hires bf16 [ci][p]
    carafe_kernel<<<dim3(16384), 256, 0, stream>>>(input2, maskb, hires_bf);
    // K4b: transpose -> hiresT bf16 [p][512]
    transpose_kernel<<<dim3(128, 8), 256, 0, stream>>>(hires_bf, bt);
    // K5: u = w_up @ hiresT + b_up (LDS-staged MFMA, 8 waves)
    mfma_conv_lds_kernel<512, 1, false><<<dim3(32, 2, 8), 512, 0, stream>>>(
        wupT, bt, bnp + 512, bnp + 768, u, 4096L * 512, 256L * 4096, 0);
    // K6: level weights -> lw0
    fuse_weights_kernel<<<dim3(512), 256, 0, stream>>>(
        input1, u, w_l1, bn_l1, w_l2, bn_l2, w_wl, b_wl, lw0g);
    // zero fusedT borders, then blend+transpose into bt
    hipMemsetAsync(bt, 0, 8L * 4356 * 256 * 2, stream);
    transpose_blend_kernel<<<dim3(128, 8), 256, 0, stream>>>(input1, u, lw0g, bt);
    // K7: final conv (LDS-staged 9-tap MFMA, 8 waves) + BN + SiLU
    mfma_conv_lds_kernel<256, 9, true><<<dim3(32, 2, 8), 512, 0, stream>>>(
        wT, bt, bnp, bnp + 256, out, 4356L * 256, 256L * 4096, 1);
}

// Round 6
// 255.814 us; speedup vs baseline: 1.2806x; 1.2806x over previous
//
#include <hip/hip_runtime.h>
#include <math.h>

// ASFF_2: N=8, C1=256, C2=512, H=64, W=64, low-res 32x32.
//  K1 down_gemm: ktT = bf16T(w_down @ input2 + b_down)  [N,34*34,128] padded
//  K2 enc_mfma: kt2 = 9-tap shifted MFMA GEMM           [N,36,1024] fp32
//  K3 softmax -> mask [N,1024,36]
//  K4 CARAFE apply -> hires bf16 [ci][p]                [N,512,4096]
//  K4b transpose -> hiresT bf16 [p][ci]
//  K5 LDS-staged MFMA gemm (BK=64): u = w_up @ hiresT   [N,256,4096]
//  K6 fuse_weights: lw0[n][p]
//  K6b transpose_blend: fusedT = bf16(i1*lw0 + u*lw1), padded [66x66][ci]
//  K7 LDS-staged 9-tap MFMA conv (BK=64) + BN + SiLU -> out

#define EPS 1e-5f
typedef unsigned short u16;
typedef __attribute__((ext_vector_type(8))) __bf16 bf16x8;
typedef __attribute__((ext_vector_type(4))) float f32x4;

__device__ inline u16 f2bf(float x) {
    union { float f; unsigned u; } v; v.f = x;
    unsigned r = v.u + 0x7FFF + ((v.u >> 16) & 1);
    return (u16)(r >> 16);
}

// ---------------- K1: fp32 tiled GEMM, bf16-transposed-padded output ----------------
__global__ __launch_bounds__(256) void down_gemm_kernel(
    const float* __restrict__ A, const float* __restrict__ B,
    const float* __restrict__ bias, u16* __restrict__ ktT)
{
    const int n = blockIdx.z;
    const float* Bn = B + (long)n * 512 * 1024;
    __shared__ __align__(16) float As[16][68];
    __shared__ __align__(16) float Bs[16][64];
    const int tid = threadIdx.x;
    const int tcol = tid & 15;
    const int trow = tid >> 4;
    const int rowBase = blockIdx.y * 64;
    const int colBase = blockIdx.x * 64;
    float acc[4][4] = {};
    for (int k0 = 0; k0 < 512; k0 += 16) {
#pragma unroll
        for (int i = 0; i < 4; ++i) {
            int idx = i * 256 + tid;
            int r = idx >> 4, cc = idx & 15;
            As[cc][r] = A[(long)(rowBase + r) * 512 + k0 + cc];
        }
#pragma unroll
        for (int i = 0; i < 4; ++i) {
            int idx = i * 256 + tid;
            int r = idx >> 6, cc = idx & 63;
            Bs[r][cc] = Bn[(long)(k0 + r) * 1024 + colBase + cc];
        }
        __syncthreads();
#pragma unroll
        for (int kk = 0; kk < 16; ++kk) {
            float4 a4 = *reinterpret_cast<const float4*>(&As[kk][trow * 4]);
            float4 b4 = *reinterpret_cast<const float4*>(&Bs[kk][tcol * 4]);
            float a[4] = {a4.x, a4.y, a4.z, a4.w};
            float b[4] = {b4.x, b4.y, b4.z, b4.w};
#pragma unroll
            for (int i = 0; i < 4; ++i)
#pragma unroll
                for (int j = 0; j < 4; ++j)
                    acc[i][j] += a[i] * b[j];
        }
        __syncthreads();
    }
    u16* Kn = ktT + (long)n * 1156 * 128;
#pragma unroll
    for (int i = 0; i < 4; ++i) {
        int ch = rowBase + trow * 4 + i;
        float bv = bias[ch];
#pragma unroll
        for (int j = 0; j < 4; ++j) {
            int p = colBase + tcol * 4 + j;
            int pr = ((p >> 5) + 1) * 34 + (p & 31) + 1;
            Kn[pr * 128 + ch] = f2bf(acc[i][j] + bv);
        }
    }
}

// ---------------- K2: encoder conv as 9-tap shifted MFMA GEMM ----------------
__global__ __launch_bounds__(64) void enc_mfma_kernel(
    const u16* __restrict__ A, const u16* __restrict__ B,
    const float* __restrict__ bias, float* __restrict__ C)
{
    const int n = blockIdx.y;
    const int lane = threadIdx.x;
    const int lr = lane & 15, lk = lane >> 4;
    const int p = blockIdx.x * 16 + lr;
    const int pr = ((p >> 5) + 1) * 34 + (p & 31) + 1;
    const u16* Bn = B + (long)n * 1156 * 128;
    const int bOff = pr * 128 + lk * 8;
    f32x4 acc[3] = {};
    for (int t = 0; t < 9; ++t) {
        const u16* At = A + t * 8192;
        const int btap = ((t / 3 - 1) * 34 + (t % 3 - 1)) * 128;
#pragma unroll
        for (int k0 = 0; k0 < 128; k0 += 32) {
            bf16x8 bf = *(const bf16x8*)(Bn + bOff + btap + k0);
#pragma unroll
            for (int mf = 0; mf < 3; ++mf) {
                bf16x8 af = *(const bf16x8*)(At + (mf * 16 + lr) * 128 + lk * 8 + k0);
                acc[mf] = __builtin_amdgcn_mfma_f32_16x16x32_bf16(af, bf, acc[mf], 0, 0, 0);
            }
        }
    }
    float* Cn = C + (long)n * 36 * 1024;
#pragma unroll
    for (int mf = 0; mf < 3; ++mf)
#pragma unroll
        for (int reg = 0; reg < 4; ++reg) {
            int co = mf * 16 + lk * 4 + reg;
            if (co < 36)
                Cn[(long)co * 1024 + p] = acc[mf][reg] + bias[co];
        }
}

// ---------------- K3: softmax over k=9 ----------------
__global__ __launch_bounds__(256) void mask_softmax_kernel(
    const float* __restrict__ kt2, float* __restrict__ mask)
{
    int gid = blockIdx.x * 256 + threadIdx.x;   // N*1024*4
    int q = gid & 3;
    int p = (gid >> 2) & 1023;
    int n = gid >> 12;
    float s[9];
    float mx = -1e30f;
#pragma unroll
    for (int k = 0; k < 9; ++k) {
        s[k] = kt2[(long)(n * 36 + k * 4 + q) * 1024 + p];
        mx = fmaxf(mx, s[k]);
    }
    float sum = 0.f;
#pragma unroll
    for (int k = 0; k < 9; ++k) { s[k] = expf(s[k] - mx); sum += s[k]; }
    float inv = 1.f / sum;
    float* mp = mask + (long)(n * 1024 + p) * 36 + q;
#pragma unroll
    for (int k = 0; k < 9; ++k) mp[k * 4] = s[k] * inv;
}

// ---------------- K4: CARAFE apply -> hires bf16 [ci][p] ----------------
__global__ __launch_bounds__(256) void carafe_kernel(
    const float* __restrict__ in2, const float* __restrict__ mask,
    u16* __restrict__ hires)
{
    int bx = blockIdx.x;            // N*32*64 : (n, h, cgroup)
    int cg = bx & 63;
    int h = (bx >> 6) & 31;
    int n = bx >> 11;
    int tid = threadIdx.x;
    int w = tid & 31;
    int cl = tid >> 5;
    int c = cg * 8 + cl;
    __shared__ float mrow[32 * 37];
    const float* mg = mask + (long)(n * 1024 + h * 32) * 36;
    for (int idx = tid; idx < 32 * 36; idx += 256) {
        int pw = idx / 36, j = idx - pw * 36;
        mrow[pw * 37 + j] = mg[idx];
    }
    __syncthreads();
    const float* ip = in2 + (long)(n * 512 + c) * 1024;
    float acc[4] = {0.f, 0.f, 0.f, 0.f};
#pragma unroll
    for (int k = 0; k < 9; ++k) {
        int dh = k / 3 - 1, dw = k % 3 - 1;
        int hh = h + dh, ww = w + dw;
        float val = (hh >= 0 && hh < 32 && ww >= 0 && ww < 32) ? ip[hh * 32 + ww] : 0.f;
#pragma unroll
        for (int q = 0; q < 4; ++q)
            acc[q] += val * mrow[w * 37 + k * 4 + q];
    }
    u16* op = hires + (long)(n * 512 + c) * 4096;
#pragma unroll
    for (int q = 0; q < 4; ++q) {
        int r1 = q >> 1, r2 = q & 1;
        op[(2 * h + r1) * 64 + 2 * w + r2] = f2bf(acc[q]);
    }
}

// ---------------- K4b: transpose hires [512][4096] -> hiresT [p][512] ----------------
__global__ __launch_bounds__(256) void transpose_kernel(
    const u16* __restrict__ src0, u16* __restrict__ dst)
{
    constexpr int C = 512, CP = 514;
    __shared__ u16 lds[32 * CP];
    const int n = blockIdx.y;
    const int p0 = blockIdx.x * 32;
    const int tid = threadIdx.x;
    {
        const int w = tid & 31;
        const int chunk = tid >> 5;
        const u16* src = src0 + (long)n * C * 4096 + p0 + w;
        for (int ci = chunk * 64; ci < chunk * 64 + 64; ++ci)
            lds[w * CP + ci] = src[(long)ci * 4096];
    }
    __syncthreads();
    const int px = tid >> 3;
    const int q = tid & 7;
    u16* drow = dst + (long)n * 4096 * C + (long)(p0 + px) * C;
    const u16* lrow = lds + px * CP;
#pragma unroll
    for (int j = 0; j < C / 16; ++j) {
        int off = j * 16 + q * 2;
        *(unsigned*)(drow + off) = *(const unsigned*)(lrow + off);
    }
}

// ---------------- K6b: fused blend + transpose-cast to padded fusedT ----------------
__global__ __launch_bounds__(256) void transpose_blend_kernel(
    const float* __restrict__ i1g, const float* __restrict__ ug,
    const float* __restrict__ lw0g, u16* __restrict__ dst)
{
    constexpr int C = 256, CP = 258;
    __shared__ u16 lds[32 * CP];
    const int n = blockIdx.y;
    const int p0 = blockIdx.x * 32;
    const int tid = threadIdx.x;
    {
        const int w = tid & 31;
        const int chunk = tid >> 5;
        const int p = p0 + w;
        const float lw = lw0g[n * 4096 + p];
        const float lw1 = 1.f - lw;
        const float* s1 = i1g + (long)n * C * 4096 + p;
        const float* s2 = ug + (long)n * C * 4096 + p;
        for (int ci = chunk * 32; ci < chunk * 32 + 32; ++ci)
            lds[w * CP + ci] = f2bf(s1[(long)ci * 4096] * lw + s2[(long)ci * 4096] * lw1);
    }
    __syncthreads();
    const int px = tid >> 3;
    const int q = tid & 7;
    const int p = p0 + px;
    long prow = (long)((p >> 6) + 1) * 66 + (p & 63) + 1;
    u16* drow = dst + (long)n * 4356 * C + prow * C;
    const u16* lrow = lds + px * CP;
#pragma unroll
    for (int j = 0; j < C / 16; ++j) {
        int off = j * 16 + q * 2;
        *(unsigned*)(drow + off) = *(const unsigned*)(lrow + off);
    }
}

// ---------------- K5/K7: LDS-staged MFMA shifted-GEMM, BK=64 ----------------
// 128x128 tile, 4 waves 2Mx2N (wave tile 64x64). B staged per 64-ci step via
// global_load_lds(16B), double-buffered; region covers all NT taps. LDS row =
// 64ci = 8x16B units; XOR-swizzle unit by (row&7) via pre-swizzled global src.
#define STAGE(bufi, k0s)                                                              \
    for (int i = wid; i < NLOAD; i += 4) {                                            \
        int f = i * 64 + lane;                                                        \
        int r = f >> 3;                                                               \
        int us = (f & 7) ^ (r & 7);                                                   \
        const u16* gsrc = Bn + (long)(g0 + r) * KC + (k0s) + us * 8;                  \
        __builtin_amdgcn_global_load_lds(                                             \
            (const __attribute__((address_space(1))) void*)gsrc,                      \
            (__attribute__((address_space(3))) void*)(lds + (bufi) * BUFU + i * 512), \
            16, 0, 0);                                                                \
    }

template<int KC, int NT, bool PADDED>
__global__ __launch_bounds__(256, 2) void mfma_conv_lds_kernel(
    const u16* __restrict__ A,      // [NT][256][KC] bf16
    const u16* __restrict__ B,      // per image [rows][KC] bf16
    const float* __restrict__ scale, const float* __restrict__ shift,
    float* __restrict__ C, long strideB, long strideC, int silu)
{
    constexpr int RROWS = PADDED ? 264 : 128;   // 4 padded image rows x 66 | 128 cols
    constexpr int NLOAD = RROWS / 8;            // 33 | 16 insts per buffer (1KB each)
    constexpr int BUFU  = RROWS * 64;           // u16 per buffer (64 ci/row)
    __shared__ __align__(16) u16 lds[2 * BUFU];
    const int n = blockIdx.z;
    const u16* Bn = B + (long)n * strideB;
    float* Cn = C + (long)n * strideC;
    const int tid = threadIdx.x;
    const int lane = tid & 63;
    const int wid = tid >> 6;                   // 0..3
    const int mw = wid >> 1, nw = wid & 1;      // 2M x 2N
    const int lr = lane & 15, lk = lane >> 4;
    const int rowBase = blockIdx.y * 128;
    const int colBase = blockIdx.x * 128;
    const int g0 = PADDED ? (colBase >> 6) * 66 : colBase;

    long aBase[4];
#pragma unroll
    for (int mf = 0; mf < 4; ++mf)
        aBase[mf] = (long)(rowBase + mw * 64 + mf * 16 + lr) * KC + lk * 8;

    f32x4 acc[4][4] = {};
    bf16x8 af[4][2], afn[4][2];
#pragma unroll
    for (int mf = 0; mf < 4; ++mf)
#pragma unroll
        for (int h = 0; h < 2; ++h)
            af[mf][h] = *(const bf16x8*)(A + aBase[mf] + h * 32);   // (t=0, k0=0)
    STAGE(0, 0);

    constexpr int NK = KC / 64;
    int cur = 0;
    for (int kx = 0; kx < NK; ++kx) {
        __syncthreads();                                 // drains staging of lds[cur]
        if (kx + 1 < NK) { STAGE(cur ^ 1, (kx + 1) * 64); }
#pragma unroll
        for (int t = 0; t < NT; ++t) {
            // prefetch A for next tap (or next k0's tap 0)
            int tn = (t + 1 == NT) ? 0 : t + 1;
            int kn = (t + 1 == NT) ? ((kx + 1 < NK) ? (kx + 1) * 64 : 0) : kx * 64;
            const u16* An = A + (long)tn * 256 * KC + kn;
#pragma unroll
            for (int mf = 0; mf < 4; ++mf)
#pragma unroll
                for (int h = 0; h < 2; ++h)
                    afn[mf][h] = *(const bf16x8*)(An + aBase[mf] + h * 32);
            int rb;
            if (PADDED) {
                int dh = t / 3 - 1, dw = t % 3 - 1;
                rb = (nw + dh + 1) * 66 + dw + 1 + lr;
            } else {
                rb = nw * 64 + lr;
            }
#pragma unroll
            for (int h = 0; h < 2; ++h) {
                bf16x8 bfr[4];
#pragma unroll
                for (int nf = 0; nf < 4; ++nf) {
                    int r = rb + nf * 16;
                    bfr[nf] = *(const bf16x8*)(lds + cur * BUFU + r * 64 +
                                               ((lk + h * 4) ^ (r & 7)) * 8);
                }
#pragma unroll
                for (int mf = 0; mf < 4; ++mf)
#pragma unroll
                    for (int nf = 0; nf < 4; ++nf)
                        acc[mf][nf] = __builtin_amdgcn_mfma_f32_16x16x32_bf16(
                            af[mf][h], bfr[nf], acc[mf][nf], 0, 0, 0);
            }
#pragma unroll
            for (int mf = 0; mf < 4; ++mf)
#pragma unroll
                for (int h = 0; h < 2; ++h)
                    af[mf][h] = afn[mf][h];
        }
        cur ^= 1;
    }
#pragma unroll
    for (int mf = 0; mf < 4; ++mf) {
#pragma unroll
        for (int reg = 0; reg < 4; ++reg) {
            int co = rowBase + mw * 64 + mf * 16 + lk * 4 + reg;
            float sc = scale[co], sh = shift[co];
#pragma unroll
            for (int nf = 0; nf < 4; ++nf) {
                int col = colBase + nw * 64 + nf * 16 + lr;
                float y = acc[mf][nf][reg] * sc + sh;
                if (silu) y = y / (1.f + expf(-y));
                Cn[(long)co * 4096 + col] = y;
            }
        }
    }
}

// ---------------- K6: level weights (softmax over 2) -> lw0[n][p] ----------------
__global__ __launch_bounds__(256) void fuse_weights_kernel(
    const float* __restrict__ input1, const float* __restrict__ u,
    const float* __restrict__ w_l1, const float* __restrict__ bn_l1,
    const float* __restrict__ w_l2, const float* __restrict__ bn_l2,
    const float* __restrict__ w_wl, const float* __restrict__ b_wl,
    float* __restrict__ lw0g)
{
    int bx = blockIdx.x;            // 8 * 64
    int n = bx >> 6;
    int p0 = (bx & 63) * 64;
    int tid = threadIdx.x;
    int pos = tid & 63;
    int chunk = tid >> 6;
    int p = p0 + pos;
    const float* i1 = input1 + (long)n * 256 * 4096;
    const float* i2 = u + (long)n * 256 * 4096;
    float s1[8] = {}, s2[8] = {};
    for (int ci = chunk * 64; ci < chunk * 64 + 64; ++ci) {
        float x1 = i1[(long)ci * 4096 + p];
        float x2 = i2[(long)ci * 4096 + p];
#pragma unroll
        for (int j = 0; j < 8; ++j) {
            s1[j] += w_l1[j * 256 + ci] * x1;
            s2[j] += w_l2[j * 256 + ci] * x2;
        }
    }
    __shared__ float red[4][64][16];
#pragma unroll
    for (int j = 0; j < 8; ++j) { red[chunk][pos][j] = s1[j]; red[chunk][pos][8 + j] = s2[j]; }
    __syncthreads();
    if (tid < 64) {
        float v[16];
#pragma unroll
        for (int j = 0; j < 16; ++j)
            v[j] = red[0][tid][j] + red[1][tid][j] + red[2][tid][j] + red[3][tid][j];
        float z0 = b_wl[0], z1 = b_wl[1];
#pragma unroll
        for (int j = 0; j < 8; ++j) {
            float g = bn_l1[j], b = bn_l1[8 + j], m = bn_l1[16 + j], va = bn_l1[24 + j];
            float y = (v[j] - m) * (g * rsqrtf(va + EPS)) + b;
            float sv = y / (1.f + expf(-y));
            z0 += w_wl[j] * sv;
            z1 += w_wl[16 + j] * sv;
            g = bn_l2[j]; b = bn_l2[8 + j]; m = bn_l2[16 + j]; va = bn_l2[24 + j];
            y = (v[8 + j] - m) * (g * rsqrtf(va + EPS)) + b;
            sv = y / (1.f + expf(-y));
            z0 += w_wl[8 + j] * sv;
            z1 += w_wl[24 + j] * sv;
        }
        lw0g[n * 4096 + p0 + tid] = 1.f / (1.f + expf(z1 - z0));
    }
}

// ---------------- prep kernels ----------------
__global__ __launch_bounds__(256) void prep_w_kernel(
    const float* __restrict__ w_conv, const float* __restrict__ w_up,
    const float* __restrict__ w_enc,
    u16* __restrict__ wT, u16* __restrict__ wupT, u16* __restrict__ wencT)
{
    int gid = blockIdx.x * 256 + threadIdx.x;
    if (gid < 589824) {             // wT[t][co][ci] = w_conv[co][ci][t]
        int t = gid >> 16;
        int co = (gid >> 8) & 255;
        int ci = gid & 255;
        wT[gid] = f2bf(w_conv[(co * 256 + ci) * 9 + t]);
    }
    if (gid < 131072) wupT[gid] = f2bf(w_up[gid]);
    if (gid < 73728) {              // wencT[t][co<64][ci] (zeros co>=36)
        int t = gid >> 13;
        int co = (gid >> 7) & 63;
        int ci = gid & 127;
        wencT[gid] = (co < 36) ? f2bf(w_enc[(co * 128 + ci) * 9 + t]) : (u16)0;
    }
}

__global__ void prep_bn_kernel(const float* __restrict__ bn_conv,
                               const float* __restrict__ b_up, float* __restrict__ bnp)
{
    int i = threadIdx.x;            // 256
    float g = bn_conv[i], b = bn_conv[256 + i], m = bn_conv[512 + i], v = bn_conv[768 + i];
    float sc = g * rsqrtf(v + EPS);
    bnp[i] = sc;
    bnp[256 + i] = b - m * sc;
    bnp[512 + i] = 1.f;
    bnp[768 + i] = b_up[i];
}

extern "C" void kernel_launch(void* const* d_in, const int* in_sizes, int n_in,
                              void* d_out, int out_size, void* d_ws, size_t ws_size,
                              hipStream_t stream)
{
    const float* input1 = (const float*)d_in[0];
    const float* input2 = (const float*)d_in[1];
    const float* w_down = (const float*)d_in[2];
    const float* b_down = (const float*)d_in[3];
    const float* w_enc  = (const float*)d_in[4];
    const float* b_enc  = (const float*)d_in[5];
    const float* w_up   = (const float*)d_in[6];
    const float* b_up   = (const float*)d_in[7];
    const float* w_l1   = (const float*)d_in[8];
    const float* bn_l1  = (const float*)d_in[9];
    const float* w_l2   = (const float*)d_in[10];
    const float* bn_l2  = (const float*)d_in[11];
    const float* w_wl   = (const float*)d_in[12];
    const float* b_wl   = (const float*)d_in[13];
    const float* w_conv = (const float*)d_in[14];
    const float* bn_conv= (const float*)d_in[15];
    float* out = (float*)d_out;

    // workspace layout (float units). ~108 MB total.
    float* ws     = (float*)d_ws;
    float* ktTf   = ws;                      //   591,872 f : ktT bf16 [n][1156][128]
    float* wencTf = ktTf + 591872;           //    36,864 f : wencT bf16 [9][64][128]
    float* kt2    = wencTf + 36864;          //   294,912 f
    float* maskb  = kt2 + 294912;            //   294,912 f
    float* u      = maskb + 294912;          // 8,388,608 f
    float* hireb  = u + 8388608;             // 8,388,608 f : hires bf16 [ci][p]
    float* btb    = hireb + 8388608;         // 8,388,608 f : hiresT / fusedT bf16
    float* wTf    = btb + 8388608;           //   294,912 f
    float* wupTf  = wTf + 294912;            //    65,536 f
    float* bnp    = wupTf + 65536;           //     1,024 f
    float* lw0g   = bnp + 1024;              //    32,768 f : lw0 [8][4096]
    u16* ktT      = (u16*)ktTf;
    u16* wencT    = (u16*)wencTf;
    u16* hires_bf = (u16*)hireb;
    u16* bt       = (u16*)btb;
    u16* wT       = (u16*)wTf;
    u16* wupT     = (u16*)wupTf;

    // prep (independent of data pipeline)
    prep_w_kernel<<<dim3(2304), 256, 0, stream>>>(w_conv, w_up, w_enc, wT, wupT, wencT);
    prep_bn_kernel<<<dim3(1), 256, 0, stream>>>(bn_conv, b_up, bnp);

    // K1: ktT = bf16T(w_down @ input2 + b_down), padded 34x34 grid
    hipMemsetAsync(ktT, 0, 8L * 1156 * 128 * 2, stream);
    down_gemm_kernel<<<dim3(16, 2, 8), 256, 0, stream>>>(w_down, input2, b_down, ktT);
    // K2: kt2 = 9-tap shifted MFMA GEMM
    enc_mfma_kernel<<<dim3(64, 8), 64, 0, stream>>>(wencT, ktT, b_enc, kt2);
    // K3
    mask_softmax_kernel<<<dim3(128), 256, 0, stream>>>(kt2, maskb);
    // K4: CARAFE -> hires bf16 [ci][p]
    carafe_kernel<<<dim3(16384), 256, 0, stream>>>(input2, maskb, hires_bf);
    // K4b: transpose -> hiresT bf16 [p][512]
    transpose_kernel<<<dim3(128, 8), 256, 0, stream>>>(hires_bf, bt);
    // K5: u = w_up @ hiresT + b_up (LDS-staged MFMA, BK=64)
    mfma_conv_lds_kernel<512, 1, false><<<dim3(32, 2, 8), 256, 0, stream>>>(
        wupT, bt, bnp + 512, bnp + 768, u, 4096L * 512, 256L * 4096, 0);
    // K6: level weights -> lw0
    fuse_weights_kernel<<<dim3(512), 256, 0, stream>>>(
        input1, u, w_l1, bn_l1, w_l2, bn_l2, w_wl, b_wl, lw0g);
    // zero fusedT borders, then blend+transpose into bt
    hipMemsetAsync(bt, 0, 8L * 4356 * 256 * 2, stream);
    transpose_blend_kernel<<<dim3(128, 8), 256, 0, stream>>>(input1, u, lw0g, bt);
    // K7: final conv (LDS-staged 9-tap MFMA, BK=64) + BN + SiLU
    mfma_conv_lds_kernel<256, 9, true><<<dim3(32, 2, 8), 256, 0, stream>>>(
        wT, bt, bnp, bnp + 256, out, 4356L * 256, 256L * 4096, 1);
}